// Round 1
// baseline (249.191 us; speedup 1.0000x reference)
//
#include <hip/hip_runtime.h>
#include <hip/hip_bf16.h>
#include <math.h>

#define BB 2
#define HH 64
#define WW 64
#define CC 128
#define NH 4
#define HD 32
#define KK 7

// ---------------------------------------------------------------------------
// K1: t -> sinusoidal emb -> silu -> @ ln_w + ln_b  => ada [B, 2C]
// ---------------------------------------------------------------------------
__global__ __launch_bounds__(256) void k_ada(const int* __restrict__ t,
                                             const float* __restrict__ ln_w,
                                             const float* __restrict__ ln_b,
                                             float* __restrict__ ada) {
    __shared__ float s_emb[CC];
    const int j = threadIdx.x;  // 0..255
    for (int b = 0; b < BB; ++b) {
        const float tf = (float)t[b] / 100.0f * 4000.0f;
        if (j < CC) {
            const int i = j & 63;
            const float freq = expf((float)i * (-logf(10000.0f) / 63.0f));
            const float e = tf * freq;
            const float em = (j < 64) ? sinf(e) : cosf(e);
            s_emb[j] = em / (1.0f + expf(-em));  // silu
        }
        __syncthreads();
        float acc = ln_b[j];
        #pragma unroll 4
        for (int c = 0; c < CC; ++c) acc += s_emb[c] * ln_w[c * 2 * CC + j];
        ada[b * 2 * CC + j] = acc;
        __syncthreads();
    }
}

// ---------------------------------------------------------------------------
// K2: per-pixel LayerNorm + AdaLN affine + qkv GEMV.
// block = 128 threads = one pixel. q scaled by HD^-0.5.
// q/k/v written as [B][NH][H][W][HD].
// ---------------------------------------------------------------------------
__global__ __launch_bounds__(128) void k_lnqkv(const float* __restrict__ x,
                                               const float* __restrict__ ada,
                                               const float* __restrict__ qkv_w,
                                               const float* __restrict__ qkv_b,
                                               float* __restrict__ q,
                                               float* __restrict__ k,
                                               float* __restrict__ v) {
    const int pix = blockIdx.x;   // b*4096 + h*64 + w
    const int tid = threadIdx.x;  // 0..127
    const int b = pix >> 12;
    __shared__ float s_y[CC];
    __shared__ float s_red[4];

    const float xv = x[(size_t)pix * CC + tid];
    float s = xv, ss = xv * xv;
    #pragma unroll
    for (int o = 32; o > 0; o >>= 1) {
        s  += __shfl_down(s, o, 64);
        ss += __shfl_down(ss, o, 64);
    }
    const int wid = tid >> 6;
    if ((tid & 63) == 0) { s_red[wid * 2] = s; s_red[wid * 2 + 1] = ss; }
    __syncthreads();
    const float sum   = s_red[0] + s_red[2];
    const float sumsq = s_red[1] + s_red[3];
    const float mean = sum * (1.0f / CC);
    const float var  = sumsq * (1.0f / CC) - mean * mean;
    const float rstd = rsqrtf(var + 1e-5f);
    const float sc = ada[b * 256 + tid];
    const float sh = ada[b * 256 + 128 + tid];
    s_y[tid] = (xv - mean) * rstd * (1.0f + sc) + sh;
    __syncthreads();

    float a0 = qkv_b[tid];
    float a1 = qkv_b[tid + 128];
    float a2 = qkv_b[tid + 256];
    #pragma unroll 4
    for (int c = 0; c < CC; ++c) {
        const float yv = s_y[c];
        const float* wr = qkv_w + (size_t)c * 384 + tid;
        a0 = fmaf(yv, wr[0],   a0);
        a1 = fmaf(yv, wr[128], a1);
        a2 = fmaf(yv, wr[256], a2);
    }
    const int hw = pix & 4095;
    const int n = tid >> 5, d = tid & 31;
    const size_t dst = ((size_t)(b * NH + n) * (HH * WW) + hw) * HD + d;
    q[dst] = a0 * 0.17677669529663687f;  // 1/sqrt(32)
    k[dst] = a1;
    v[dst] = a2;
}

// ---------------------------------------------------------------------------
// K3: neighborhood attention, one thread per query (b,n,h,w).
// Online softmax over the 49 keys; q and out accumulator in registers.
// ---------------------------------------------------------------------------
__global__ __launch_bounds__(256) void k_attn(const float* __restrict__ q,
                                              const float* __restrict__ k,
                                              const float* __restrict__ v,
                                              const float* __restrict__ rpb,
                                              float* __restrict__ attn_out) {
    const int gid = blockIdx.x * blockDim.x + threadIdx.x;  // b*16384+n*4096+h*64+w
    if (gid >= BB * NH * HH * WW) return;
    const int w = gid & 63;
    const int h = (gid >> 6) & 63;
    const int n = (gid >> 12) & 3;
    const int b = gid >> 14;

    float qr[HD];
    const float* qp = q + (size_t)gid * HD;
    #pragma unroll
    for (int d = 0; d < HD; d += 4) {
        const float4 t4 = *(const float4*)(qp + d);
        qr[d] = t4.x; qr[d + 1] = t4.y; qr[d + 2] = t4.z; qr[d + 3] = t4.w;
    }

    const int hs = min(max(h - 3, 0), HH - KK);
    const int ws = min(max(w - 3, 0), WW - KK);
    const float* rp = rpb + n * 13 * 13;

    float m = -1e30f, l = 0.0f;
    float acc[HD];
    #pragma unroll
    for (int d = 0; d < HD; ++d) acc[d] = 0.0f;

    for (int a = 0; a < KK; ++a) {
        const int kh = hs + a;
        const int rh = kh - h + 6;
        const size_t rowbase = (((size_t)(b * NH + n) * HH + kh) * WW + ws) * HD;
        const float* kbase = k + rowbase;
        const float* vbase = v + rowbase;
        #pragma unroll
        for (int c = 0; c < KK; ++c) {
            const int rw = ws + c - w + 6;
            const float* kp = kbase + c * HD;
            float sdot = 0.0f;
            #pragma unroll
            for (int d = 0; d < HD; d += 4) {
                const float4 k4 = *(const float4*)(kp + d);
                sdot = fmaf(qr[d], k4.x, sdot);
                sdot = fmaf(qr[d + 1], k4.y, sdot);
                sdot = fmaf(qr[d + 2], k4.z, sdot);
                sdot = fmaf(qr[d + 3], k4.w, sdot);
            }
            sdot += rp[rh * 13 + rw];
            const float mnew = fmaxf(m, sdot);
            const float corr = __expf(m - mnew);
            const float p = __expf(sdot - mnew);
            l = l * corr + p;
            const float* vp = vbase + c * HD;
            #pragma unroll
            for (int d = 0; d < HD; d += 4) {
                const float4 v4 = *(const float4*)(vp + d);
                acc[d]     = fmaf(p, v4.x, acc[d]     * corr);
                acc[d + 1] = fmaf(p, v4.y, acc[d + 1] * corr);
                acc[d + 2] = fmaf(p, v4.z, acc[d + 2] * corr);
                acc[d + 3] = fmaf(p, v4.w, acc[d + 3] * corr);
            }
            m = mnew;
        }
    }
    const float inv = 1.0f / l;
    const int hw = gid & 4095;
    float* op = attn_out + ((size_t)(b * (HH * WW) + hw)) * CC + n * HD;
    #pragma unroll
    for (int d = 0; d < HD; ++d) op[d] = acc[d] * inv;
}

// ---------------------------------------------------------------------------
// K4: out = attn_y @ proj_w + proj_b.  block = 128 threads = one pixel.
// ---------------------------------------------------------------------------
__global__ __launch_bounds__(128) void k_proj(const float* __restrict__ y,
                                              const float* __restrict__ proj_w,
                                              const float* __restrict__ proj_b,
                                              float* __restrict__ out) {
    const int pix = blockIdx.x;
    const int tid = threadIdx.x;
    __shared__ float s_y[CC];
    s_y[tid] = y[(size_t)pix * CC + tid];
    __syncthreads();
    float acc = proj_b[tid];
    #pragma unroll 4
    for (int c = 0; c < CC; ++c)
        acc = fmaf(s_y[c], proj_w[(size_t)c * CC + tid], acc);
    out[(size_t)pix * CC + tid] = acc;
}

extern "C" void kernel_launch(void* const* d_in, const int* in_sizes, int n_in,
                              void* d_out, int out_size, void* d_ws, size_t ws_size,
                              hipStream_t stream) {
    const float* x      = (const float*)d_in[0];
    // d_in[1] = cond (unused by the reference forward path)
    const int*   t      = (const int*)d_in[2];
    const float* ln_w   = (const float*)d_in[3];
    const float* ln_b   = (const float*)d_in[4];
    const float* qkv_w  = (const float*)d_in[5];
    const float* qkv_b  = (const float*)d_in[6];
    const float* rpb    = (const float*)d_in[7];
    const float* proj_w = (const float*)d_in[8];
    const float* proj_b = (const float*)d_in[9];
    float* out = (float*)d_out;

    float* ws = (float*)d_ws;
    const size_t NPIX = (size_t)BB * HH * WW;          // 8192
    const size_t QSZ  = (size_t)BB * NH * HH * WW * HD; // 1048576
    float* ada  = ws;
    float* q    = ws + 512;
    float* k    = q + QSZ;
    float* v    = k + QSZ;
    float* attn = v + QSZ;

    k_ada<<<1, 256, 0, stream>>>(t, ln_w, ln_b, ada);
    k_lnqkv<<<(int)NPIX, 128, 0, stream>>>(x, ada, qkv_w, qkv_b, q, k, v);
    k_attn<<<(BB * NH * HH * WW) / 256, 256, 0, stream>>>(q, k, v, rpb, attn);
    k_proj<<<(int)NPIX, 128, 0, stream>>>(attn, proj_w, proj_b, out);
}

// Round 2
// 193.678 us; speedup vs baseline: 1.2866x; 1.2866x over previous
//
#include <hip/hip_runtime.h>
#include <hip/hip_bf16.h>
#include <math.h>

#define BB 2
#define HH 64
#define WW 64
#define CC 128
#define NH 4
#define HD 32
#define KK 7
#define PPB 16   // pixels per block for the GEMV kernels

// ---------------------------------------------------------------------------
// K1: t -> sinusoidal emb -> silu -> @ ln_w + ln_b  => ada [B, 2C]
// ---------------------------------------------------------------------------
__global__ __launch_bounds__(256) void k_ada(const int* __restrict__ t,
                                             const float* __restrict__ ln_w,
                                             const float* __restrict__ ln_b,
                                             float* __restrict__ ada) {
    __shared__ float s_emb[CC];
    const int j = threadIdx.x;  // 0..255
    for (int b = 0; b < BB; ++b) {
        const float tf = (float)t[b] / 100.0f * 4000.0f;
        if (j < CC) {
            const int i = j & 63;
            const float freq = expf((float)i * (-logf(10000.0f) / 63.0f));
            const float e = tf * freq;
            const float em = (j < 64) ? sinf(e) : cosf(e);
            s_emb[j] = em / (1.0f + expf(-em));  // silu
        }
        __syncthreads();
        float acc = ln_b[j];
        #pragma unroll 4
        for (int c = 0; c < CC; ++c) acc += s_emb[c] * ln_w[c * 2 * CC + j];
        ada[b * 2 * CC + j] = acc;
        __syncthreads();
    }
}

// ---------------------------------------------------------------------------
// K2: LayerNorm + AdaLN + qkv GEMV, 16 pixels per 128-thread block.
// Weight matrix read ONCE per block (16x reuse vs per-pixel blocks).
// q/k/v written as [B][NH][H*W][HD]; q pre-scaled by HD^-0.5.
// ---------------------------------------------------------------------------
__global__ __launch_bounds__(128) void k_lnqkv(const float* __restrict__ x,
                                               const float* __restrict__ ada,
                                               const float* __restrict__ qkv_w,
                                               const float* __restrict__ qkv_b,
                                               float* __restrict__ q,
                                               float* __restrict__ k,
                                               float* __restrict__ v) {
    const int tid = threadIdx.x;       // 0..127
    const int pix0 = blockIdx.x * PPB; // 16 pixels, all same batch b
    const int b = pix0 >> 12;
    __shared__ float s_y[PPB][CC];
    __shared__ float s_red[4];

    const float sc = 1.0f + ada[b * 256 + tid];
    const float sh = ada[b * 256 + 128 + tid];

    // Phase 1: LN + affine for 16 pixels
    for (int p = 0; p < PPB; ++p) {
        const float xv = x[(size_t)(pix0 + p) * CC + tid];
        float s = xv, ss = xv * xv;
        #pragma unroll
        for (int o = 32; o > 0; o >>= 1) {
            s  += __shfl_down(s, o, 64);
            ss += __shfl_down(ss, o, 64);
        }
        if ((tid & 63) == 0) { s_red[(tid >> 6) * 2] = s; s_red[(tid >> 6) * 2 + 1] = ss; }
        __syncthreads();
        const float mean = (s_red[0] + s_red[2]) * (1.0f / CC);
        const float var  = (s_red[1] + s_red[3]) * (1.0f / CC) - mean * mean;
        const float rstd = rsqrtf(var + 1e-5f);
        s_y[p][tid] = (xv - mean) * rstd * sc + sh;
        __syncthreads();
    }

    // Phase 2: GEMV, thread tid owns output column tid of each of q/k/v
    float aq[PPB], ak[PPB], av[PPB];
    const float qb0 = qkv_b[tid], qb1 = qkv_b[tid + 128], qb2 = qkv_b[tid + 256];
    #pragma unroll
    for (int p = 0; p < PPB; ++p) { aq[p] = qb0; ak[p] = qb1; av[p] = qb2; }

    for (int c = 0; c < CC; c += 4) {
        float w0[4], w1[4], w2[4];
        #pragma unroll
        for (int i = 0; i < 4; ++i) {
            const float* wr = qkv_w + (size_t)(c + i) * 384 + tid;
            w0[i] = wr[0]; w1[i] = wr[128]; w2[i] = wr[256];
        }
        #pragma unroll
        for (int p = 0; p < PPB; ++p) {
            const float4 y4 = *(const float4*)&s_y[p][c];
            aq[p] = fmaf(y4.x, w0[0], fmaf(y4.y, w0[1], fmaf(y4.z, w0[2], fmaf(y4.w, w0[3], aq[p]))));
            ak[p] = fmaf(y4.x, w1[0], fmaf(y4.y, w1[1], fmaf(y4.z, w1[2], fmaf(y4.w, w1[3], ak[p]))));
            av[p] = fmaf(y4.x, w2[0], fmaf(y4.y, w2[1], fmaf(y4.z, w2[2], fmaf(y4.w, w2[3], av[p]))));
        }
    }

    const int n = tid >> 5, d = tid & 31;
    #pragma unroll
    for (int p = 0; p < PPB; ++p) {
        const int hw = (pix0 + p) & 4095;
        const size_t dst = ((size_t)(b * NH + n) * (HH * WW) + hw) * HD + d;
        q[dst] = aq[p] * 0.17677669529663687f;  // 1/sqrt(32)
        k[dst] = ak[p];
        v[dst] = av[p];
    }
}

// ---------------------------------------------------------------------------
// K3: neighborhood attention, 8 lanes per query (4 dims each).
// Dot product via shfl_xor(width=8); softmax state replicated per lane.
// ---------------------------------------------------------------------------
__global__ __launch_bounds__(256) void k_attn(const float* __restrict__ q,
                                              const float* __restrict__ k,
                                              const float* __restrict__ v,
                                              const float* __restrict__ rpb,
                                              float* __restrict__ attn_out) {
    const int gt = blockIdx.x * blockDim.x + threadIdx.x;
    const int query = gt >> 3;            // b*16384 + n*4096 + h*64 + w
    const int d0 = (gt & 7) * 4;
    const int w = query & 63;
    const int h = (query >> 6) & 63;
    const int n = (query >> 12) & 3;
    const int b = query >> 14;

    const float4 q4 = *(const float4*)(q + (size_t)query * HD + d0);

    const int hs = min(max(h - 3, 0), HH - KK);
    const int ws = min(max(w - 3, 0), WW - KK);
    const float* rp = rpb + n * 13 * 13;

    float m = -1e30f, l = 0.0f;
    float ax = 0.f, ay = 0.f, az = 0.f, aw = 0.f;

    for (int a = 0; a < KK; ++a) {
        const int kh = hs + a;
        const int rh = kh - h + 6;
        const size_t rowbase = (((size_t)(b * NH + n) * HH + kh) * WW + ws) * HD + d0;
        const float* kbase = k + rowbase;
        const float* vbase = v + rowbase;
        #pragma unroll
        for (int c = 0; c < KK; ++c) {
            const int rw = ws + c - w + 6;
            const float4 k4 = *(const float4*)(kbase + c * HD);
            float sdot = fmaf(q4.x, k4.x, fmaf(q4.y, k4.y, fmaf(q4.z, k4.z, q4.w * k4.w)));
            sdot += __shfl_xor(sdot, 4, 8);
            sdot += __shfl_xor(sdot, 2, 8);
            sdot += __shfl_xor(sdot, 1, 8);
            sdot += rp[rh * 13 + rw];
            const float mnew = fmaxf(m, sdot);
            const float corr = __expf(m - mnew);
            const float p = __expf(sdot - mnew);
            l = l * corr + p;
            const float4 v4 = *(const float4*)(vbase + c * HD);
            ax = fmaf(p, v4.x, ax * corr);
            ay = fmaf(p, v4.y, ay * corr);
            az = fmaf(p, v4.z, az * corr);
            aw = fmaf(p, v4.w, aw * corr);
            m = mnew;
        }
    }
    const float inv = 1.0f / l;
    const int hw = query & 4095;
    float* op = attn_out + ((size_t)(b * (HH * WW) + hw)) * CC + n * HD + d0;
    op[0] = ax * inv; op[1] = ay * inv; op[2] = az * inv; op[3] = aw * inv;
}

// ---------------------------------------------------------------------------
// K4: out = attn_y @ proj_w + proj_b, 16 pixels per 128-thread block.
// ---------------------------------------------------------------------------
__global__ __launch_bounds__(128) void k_proj(const float* __restrict__ y,
                                              const float* __restrict__ proj_w,
                                              const float* __restrict__ proj_b,
                                              float* __restrict__ out) {
    const int tid = threadIdx.x;
    const int pix0 = blockIdx.x * PPB;
    __shared__ float s_y[PPB][CC];
    #pragma unroll
    for (int p = 0; p < PPB; p += 4) {
        // 128 threads load 4 rows of 128 floats each iteration
        const int pr = p + (tid >> 5);
        const int col = (tid & 31) * 4;
        const float4 t4 = *(const float4*)(y + (size_t)(pix0 + pr) * CC + col);
        *(float4*)&s_y[pr][col] = t4;
    }
    __syncthreads();
    float acc[PPB];
    const float pb = proj_b[tid];
    #pragma unroll
    for (int p = 0; p < PPB; ++p) acc[p] = pb;
    for (int c = 0; c < CC; c += 4) {
        float w0[4];
        #pragma unroll
        for (int i = 0; i < 4; ++i) w0[i] = proj_w[(size_t)(c + i) * CC + tid];
        #pragma unroll
        for (int p = 0; p < PPB; ++p) {
            const float4 y4 = *(const float4*)&s_y[p][c];
            acc[p] = fmaf(y4.x, w0[0], fmaf(y4.y, w0[1], fmaf(y4.z, w0[2], fmaf(y4.w, w0[3], acc[p]))));
        }
    }
    #pragma unroll
    for (int p = 0; p < PPB; ++p)
        out[(size_t)(pix0 + p) * CC + tid] = acc[p];
}

extern "C" void kernel_launch(void* const* d_in, const int* in_sizes, int n_in,
                              void* d_out, int out_size, void* d_ws, size_t ws_size,
                              hipStream_t stream) {
    const float* x      = (const float*)d_in[0];
    const int*   t      = (const int*)d_in[2];
    const float* ln_w   = (const float*)d_in[3];
    const float* ln_b   = (const float*)d_in[4];
    const float* qkv_w  = (const float*)d_in[5];
    const float* qkv_b  = (const float*)d_in[6];
    const float* rpb    = (const float*)d_in[7];
    const float* proj_w = (const float*)d_in[8];
    const float* proj_b = (const float*)d_in[9];
    float* out = (float*)d_out;

    float* ws = (float*)d_ws;
    const size_t NPIX = (size_t)BB * HH * WW;           // 8192
    const size_t QSZ  = (size_t)BB * NH * HH * WW * HD; // 1048576
    float* ada  = ws;
    float* q    = ws + 512;
    float* k    = q + QSZ;
    float* v    = k + QSZ;
    float* attn = v + QSZ;

    k_ada<<<1, 256, 0, stream>>>(t, ln_w, ln_b, ada);
    k_lnqkv<<<(int)(NPIX / PPB), 128, 0, stream>>>(x, ada, qkv_w, qkv_b, q, k, v);
    k_attn<<<(BB * NH * HH * WW * 8) / 256, 256, 0, stream>>>(q, k, v, rpb, attn);
    k_proj<<<(int)(NPIX / PPB), 128, 0, stream>>>(attn, proj_w, proj_b, out);
}

// Round 3
// 119.808 us; speedup vs baseline: 2.0799x; 1.6166x over previous
//
#include <hip/hip_runtime.h>
#include <hip/hip_bf16.h>
#include <math.h>

#define BB 2
#define HH 64
#define WW 64
#define CC 128
#define NH 4
#define HD 32
#define KK 7

typedef __attribute__((ext_vector_type(8))) short short8v;   // 8 bf16 = 4 VGPR
typedef __attribute__((ext_vector_type(4))) float float4v;

__device__ __forceinline__ unsigned short f2bf(float f) {
    union { float f; unsigned int u; } c; c.f = f;
    unsigned int r = c.u + 0x7FFFu + ((c.u >> 16) & 1u);  // RNE
    return (unsigned short)(r >> 16);
}

// ---------------------------------------------------------------------------
// K0: block 0: ada = silu(sinemb(t)) @ ln_w + ln_b
//     blocks 1..256: wT_qkv[384][128], wT_proj[128][128] bf16 transposed casts
// ---------------------------------------------------------------------------
__global__ __launch_bounds__(256) void k_prep(const int* __restrict__ t,
                                              const float* __restrict__ ln_w,
                                              const float* __restrict__ ln_b,
                                              const float* __restrict__ qkv_w,
                                              const float* __restrict__ proj_w,
                                              float* __restrict__ ada,
                                              unsigned short* __restrict__ wTq,
                                              unsigned short* __restrict__ wTp) {
    const int j = threadIdx.x;
    if (blockIdx.x == 0) {
        __shared__ float s_emb[CC];
        for (int b = 0; b < BB; ++b) {
            const float tf = (float)t[b] / 100.0f * 4000.0f;
            if (j < CC) {
                const int i = j & 63;
                const float freq = expf((float)i * (-logf(10000.0f) / 63.0f));
                const float e = tf * freq;
                const float em = (j < 64) ? sinf(e) : cosf(e);
                s_emb[j] = em / (1.0f + expf(-em));
            }
            __syncthreads();
            float acc = ln_b[j];
            #pragma unroll 4
            for (int c = 0; c < CC; ++c) acc += s_emb[c] * ln_w[c * 2 * CC + j];
            ada[b * 2 * CC + j] = acc;
            __syncthreads();
        }
    } else {
        int idx = (blockIdx.x - 1) * 256 + j;   // flat output index
        if (idx < 384 * 128) {
            const int n = idx >> 7, c = idx & 127;
            wTq[idx] = f2bf(qkv_w[c * 384 + n]);
        } else {
            idx -= 384 * 128;
            const int n = idx >> 7, c = idx & 127;
            wTp[idx] = f2bf(proj_w[c * 128 + n]);
        }
    }
}

// ---------------------------------------------------------------------------
// K1: LN + AdaLN + qkv GEMM via MFMA. 256 thr = 4 waves, 16 pixels/block.
// Wave wv owns output columns [wv*96, wv*96+96). B-frags in registers.
// q/k/v written [B][NH][HW][HD]; q pre-scaled by HD^-0.5.
// ---------------------------------------------------------------------------
__global__ __launch_bounds__(256) void k_lnqkv(const float* __restrict__ x,
                                               const float* __restrict__ ada,
                                               const unsigned short* __restrict__ wTq,
                                               const float* __restrict__ qkv_b,
                                               float* __restrict__ q,
                                               float* __restrict__ k,
                                               float* __restrict__ v) {
    const int tid = threadIdx.x;
    const int lane = tid & 63;
    const int wv = tid >> 6;
    const int pix0 = blockIdx.x * 16;
    const int b = pix0 >> 12;

    __shared__ unsigned short s_y[16 * 128];  // bf16 y tile, XOR-swizzled

    // --- B fragment preload (issue before LN so latency hides) ---
    const int n0 = wv * 96;
    const int bn = n0 + (lane & 15);
    const int bk = (lane >> 4) * 8;
    short8v bfrag[24];
    #pragma unroll
    for (int nt = 0; nt < 6; ++nt)
        #pragma unroll
        for (int kk = 0; kk < 4; ++kk)
            bfrag[nt * 4 + kk] =
                *(const short8v*)(wTq + (size_t)(bn + nt * 16) * 128 + kk * 32 + bk);

    // --- LN phase: 16 threads per pixel, 8 channels each ---
    const int p = tid >> 4;
    const int c0 = (tid & 15) * 8;
    const float* xp = x + (size_t)(pix0 + p) * CC + c0;
    const float4v x0 = *(const float4v*)xp;
    const float4v x1 = *(const float4v*)(xp + 4);
    float s = 0.f, ss = 0.f;
    #pragma unroll
    for (int i = 0; i < 4; ++i) { s += x0[i]; ss += x0[i] * x0[i]; }
    #pragma unroll
    for (int i = 0; i < 4; ++i) { s += x1[i]; ss += x1[i] * x1[i]; }
    #pragma unroll
    for (int o = 8; o > 0; o >>= 1) {
        s  += __shfl_xor(s, o, 16);
        ss += __shfl_xor(ss, o, 16);
    }
    const float mean = s * (1.0f / CC);
    const float var  = ss * (1.0f / CC) - mean * mean;
    const float rstd = rsqrtf(var + 1e-5f);
    const float4v sc0 = *(const float4v*)(ada + b * 256 + c0);
    const float4v sc1 = *(const float4v*)(ada + b * 256 + c0 + 4);
    const float4v sh0 = *(const float4v*)(ada + b * 256 + 128 + c0);
    const float4v sh1 = *(const float4v*)(ada + b * 256 + 128 + c0 + 4);
    short8v ypack;
    #pragma unroll
    for (int i = 0; i < 4; ++i)
        ypack[i] = (short)f2bf((x0[i] - mean) * rstd * (1.0f + sc0[i]) + sh0[i]);
    #pragma unroll
    for (int i = 0; i < 4; ++i)
        ypack[4 + i] = (short)f2bf((x1[i] - mean) * rstd * (1.0f + sc1[i]) + sh1[i]);
    {
        int o = p * 256 + (tid & 15) * 16;
        o ^= (p & 7) << 4;                       // st-swizzle (T2)
        *(short8v*)((char*)s_y + o) = ypack;
    }
    __syncthreads();

    // --- A fragments from LDS ---
    const int am = lane & 15;
    short8v afr[4];
    #pragma unroll
    for (int kk = 0; kk < 4; ++kk) {
        int o = am * 256 + kk * 64 + (lane >> 4) * 16;
        o ^= (am & 7) << 4;
        afr[kk] = *(const short8v*)((const char*)s_y + o);
    }

    float4v acc[6];
    #pragma unroll
    for (int nt = 0; nt < 6; ++nt) acc[nt] = (float4v){0.f, 0.f, 0.f, 0.f};
    #pragma unroll
    for (int nt = 0; nt < 6; ++nt)
        #pragma unroll
        for (int kk = 0; kk < 4; ++kk)
            acc[nt] = __builtin_amdgcn_mfma_f32_16x16x32_bf16(
                afr[kk], bfrag[nt * 4 + kk], acc[nt], 0, 0, 0);

    // --- epilogue: bias, q-scale, scatter to q/k/v [B][NH][HW][HD] ---
    #pragma unroll
    for (int nt = 0; nt < 6; ++nt) {
        const int n = n0 + nt * 16 + (lane & 15);
        const float bias = qkv_b[n];
        const int which = n >> 7;               // 0=q 1=k 2=v
        const int head = (n & 127) >> 5;
        const int d = n & 31;
        float* base = (which == 0) ? q : (which == 1) ? k : v;
        #pragma unroll
        for (int jj = 0; jj < 4; ++jj) {
            const int pix = pix0 + (lane >> 4) * 4 + jj;
            const int hw = pix & 4095;
            float val = acc[nt][jj] + bias;
            if (which == 0) val *= 0.17677669529663687f;
            base[((size_t)(b * NH + head) * (HH * WW) + hw) * HD + d] = val;
        }
    }
}

// ---------------------------------------------------------------------------
// K2: neighborhood attention, 8 lanes per query (4 dims each).
// ---------------------------------------------------------------------------
__global__ __launch_bounds__(256) void k_attn(const float* __restrict__ q,
                                              const float* __restrict__ k,
                                              const float* __restrict__ v,
                                              const float* __restrict__ rpb,
                                              float* __restrict__ attn_out) {
    const int gt = blockIdx.x * blockDim.x + threadIdx.x;
    const int query = gt >> 3;
    const int d0 = (gt & 7) * 4;
    const int w = query & 63;
    const int h = (query >> 6) & 63;
    const int n = (query >> 12) & 3;
    const int b = query >> 14;

    const float4 q4 = *(const float4*)(q + (size_t)query * HD + d0);

    const int hs = min(max(h - 3, 0), HH - KK);
    const int ws = min(max(w - 3, 0), WW - KK);
    const float* rp = rpb + n * 13 * 13;

    float m = -1e30f, l = 0.0f;
    float ax = 0.f, ay = 0.f, az = 0.f, aw = 0.f;

    for (int a = 0; a < KK; ++a) {
        const int kh = hs + a;
        const int rh = kh - h + 6;
        const size_t rowbase = (((size_t)(b * NH + n) * HH + kh) * WW + ws) * HD + d0;
        const float* kbase = k + rowbase;
        const float* vbase = v + rowbase;
        #pragma unroll
        for (int c = 0; c < KK; ++c) {
            const int rw = ws + c - w + 6;
            const float4 k4 = *(const float4*)(kbase + c * HD);
            float sdot = fmaf(q4.x, k4.x, fmaf(q4.y, k4.y, fmaf(q4.z, k4.z, q4.w * k4.w)));
            sdot += __shfl_xor(sdot, 4, 8);
            sdot += __shfl_xor(sdot, 2, 8);
            sdot += __shfl_xor(sdot, 1, 8);
            sdot += rp[rh * 13 + rw];
            const float mnew = fmaxf(m, sdot);
            const float corr = __expf(m - mnew);
            const float pp = __expf(sdot - mnew);
            l = l * corr + pp;
            const float4 v4 = *(const float4*)(vbase + c * HD);
            ax = fmaf(pp, v4.x, ax * corr);
            ay = fmaf(pp, v4.y, ay * corr);
            az = fmaf(pp, v4.z, az * corr);
            aw = fmaf(pp, v4.w, aw * corr);
            m = mnew;
        }
    }
    const float inv = 1.0f / l;
    const int hw = query & 4095;
    float* op = attn_out + ((size_t)(b * (HH * WW) + hw)) * CC + n * HD + d0;
    op[0] = ax * inv; op[1] = ay * inv; op[2] = az * inv; op[3] = aw * inv;
}

// ---------------------------------------------------------------------------
// K3: out = attn_y @ proj_w + proj_b via MFMA. Same structure as K1.
// Wave wv owns 32 output columns.
// ---------------------------------------------------------------------------
__global__ __launch_bounds__(256) void k_proj(const float* __restrict__ attn,
                                              const unsigned short* __restrict__ wTp,
                                              const float* __restrict__ proj_b,
                                              float* __restrict__ out) {
    const int tid = threadIdx.x;
    const int lane = tid & 63;
    const int wv = tid >> 6;
    const int pix0 = blockIdx.x * 16;

    __shared__ unsigned short s_y[16 * 128];

    const int n0 = wv * 32;
    const int bn = n0 + (lane & 15);
    const int bk = (lane >> 4) * 8;
    short8v bfrag[8];
    #pragma unroll
    for (int nt = 0; nt < 2; ++nt)
        #pragma unroll
        for (int kk = 0; kk < 4; ++kk)
            bfrag[nt * 4 + kk] =
                *(const short8v*)(wTp + (size_t)(bn + nt * 16) * 128 + kk * 32 + bk);

    // load + bf16-convert 16x128 tile
    const int p = tid >> 4;
    const int c0 = (tid & 15) * 8;
    const float* yp = attn + (size_t)(pix0 + p) * CC + c0;
    const float4v y0 = *(const float4v*)yp;
    const float4v y1 = *(const float4v*)(yp + 4);
    short8v ypack;
    #pragma unroll
    for (int i = 0; i < 4; ++i) ypack[i] = (short)f2bf(y0[i]);
    #pragma unroll
    for (int i = 0; i < 4; ++i) ypack[4 + i] = (short)f2bf(y1[i]);
    {
        int o = p * 256 + (tid & 15) * 16;
        o ^= (p & 7) << 4;
        *(short8v*)((char*)s_y + o) = ypack;
    }
    __syncthreads();

    const int am = lane & 15;
    short8v afr[4];
    #pragma unroll
    for (int kk = 0; kk < 4; ++kk) {
        int o = am * 256 + kk * 64 + (lane >> 4) * 16;
        o ^= (am & 7) << 4;
        afr[kk] = *(const short8v*)((const char*)s_y + o);
    }

    float4v acc[2];
    acc[0] = (float4v){0.f, 0.f, 0.f, 0.f};
    acc[1] = (float4v){0.f, 0.f, 0.f, 0.f};
    #pragma unroll
    for (int nt = 0; nt < 2; ++nt)
        #pragma unroll
        for (int kk = 0; kk < 4; ++kk)
            acc[nt] = __builtin_amdgcn_mfma_f32_16x16x32_bf16(
                afr[kk], bfrag[nt * 4 + kk], acc[nt], 0, 0, 0);

    #pragma unroll
    for (int nt = 0; nt < 2; ++nt) {
        const int n = n0 + nt * 16 + (lane & 15);
        const float bias = proj_b[n];
        #pragma unroll
        for (int jj = 0; jj < 4; ++jj) {
            const int pix = pix0 + (lane >> 4) * 4 + jj;
            out[(size_t)pix * CC + n] = acc[nt][jj] + bias;
        }
    }
}

extern "C" void kernel_launch(void* const* d_in, const int* in_sizes, int n_in,
                              void* d_out, int out_size, void* d_ws, size_t ws_size,
                              hipStream_t stream) {
    const float* x      = (const float*)d_in[0];
    const int*   t      = (const int*)d_in[2];
    const float* ln_w   = (const float*)d_in[3];
    const float* ln_b   = (const float*)d_in[4];
    const float* qkv_w  = (const float*)d_in[5];
    const float* qkv_b  = (const float*)d_in[6];
    const float* rpb    = (const float*)d_in[7];
    const float* proj_w = (const float*)d_in[8];
    const float* proj_b = (const float*)d_in[9];
    float* out = (float*)d_out;

    char* ws = (char*)d_ws;
    float*          ada  = (float*)ws;                       // 512 f = 2 KB
    unsigned short* wTq  = (unsigned short*)(ws + 2048);     // 384*128 bf16 = 96 KB
    unsigned short* wTp  = (unsigned short*)(ws + 2048 + 98304);  // 128*128 bf16 = 32 KB
    float*          q    = (float*)(ws + 2048 + 98304 + 32768);
    const size_t QSZ = (size_t)BB * NH * HH * WW * HD;       // 1 M floats
    float* k    = q + QSZ;
    float* v    = k + QSZ;
    float* attn = v + QSZ;

    const int NPIX = BB * HH * WW;  // 8192

    k_prep<<<257, 256, 0, stream>>>(t, ln_w, ln_b, qkv_w, proj_w, ada, wTq, wTp);
    k_lnqkv<<<NPIX / 16, 256, 0, stream>>>(x, ada, wTq, qkv_b, q, k, v);
    k_attn<<<(BB * NH * HH * WW * 8) / 256, 256, 0, stream>>>(q, k, v, rpb, attn);
    k_proj<<<NPIX / 16, 256, 0, stream>>>(attn, wTp, proj_b, out);
}